// Round 13
// baseline (49.810 us; speedup 1.0000x reference)
//
#include <hip/hip_runtime.h>
#include <hip/hip_bf16.h>

// AlignmentLoss: loss = -(sum(tril(G,-1)*eq) / (sum(tril(eq,-1)) * ||tril(G,-1)||_F))
// with G = A A^T, A: 4096x1024 fp32, target: 4096 int32 (classes < 1000).
//
//   S1 = 0.5*(sum_c ||s_c||^2 - sum_i r_i),  r_i = ||a_i||^2
//   S2 = 0.5*(sum_c n_c^2 - N)
//   S3 = 0.5*(||M||_F^2 - sum_i r_i^2),  M = A^T A  (1024x1024; ||AA^T||_F =
//        ||A^T A||_F via singular values)   [formula verified end-to-end in R9]
//   loss = -S1 / (S2 * sqrt(S3))
//
// R13 (structural): the gram moves to the D-side with full parallelism.
// Every N-side variant (R2-R12) pinned at ~30 us because 17.7 GF / 256 CUs =
// 69 MF/CU at ~45% util is ~30 us -- a per-CU work quota no schedule fixes.
// Here: FULL 64 d-tiles (no triangle, no masks) x split-K 8 = 512 blocks x
// 16.8 MF = 33.6 MF/CU (half the quota), 2 blocks/CU balanced.  No transpose
// kernel: panels staged from row-major Ab via in-register 8kx4d micro-
// transpose into XOR-swizzled [d][k] LDS.  kc = blockIdx&7 -> each XCD works
// one 1 MB row-chunk (L2-resident).  Raw fp32 partials -> 33.6 MB slab ->
// kred sums 8 chunks, squares, reduces (no masks; full Frobenius).

typedef __attribute__((ext_vector_type(8))) short short8;
typedef __attribute__((ext_vector_type(4))) float f32x4;

#define N_ROWS 4096
#define D_DIM  1024
#define N_CLS  1000
#define KC     8           // split-K chunks
#define CHUNK  512         // rows per chunk
#define KSTEPS 8           // CHUNK / 64

__device__ __forceinline__ unsigned short f2bf(float f) {
  unsigned u = __float_as_uint(f);
  u += 0x7fffu + ((u >> 16) & 1u);   // round-to-nearest-even
  return (unsigned short)(u >> 16);
}

// ---------------------------------------------------------------------------
// kprep: blocks 0..511  = convert A->bf16 + per-block fp64 partials of
//                         sum r_i AND sum r_i^2 (rowp[2b], rowp[2b+1])
//        blocks 512..   = per-class sum-vector norm + count
// ---------------------------------------------------------------------------
__global__ void __launch_bounds__(256) kprep(const float* __restrict__ A,
                                             const int* __restrict__ target,
                                             short* __restrict__ Ab,
                                             double* __restrict__ rowp,
                                             double* __restrict__ cssp,
                                             int* __restrict__ cntp) {
  const int tid = threadIdx.x, lane = tid & 63, w = tid >> 6;

  if (blockIdx.x < 512) {
    __shared__ double wr2[4], wq2[4];
    const int row0 = blockIdx.x * 8;
    double ls = 0.0, lq = 0.0;
#pragma unroll
    for (int rr = 0; rr < 2; ++rr) {
      const int i = row0 + w * 2 + rr;
      const float4* src = (const float4*)(A + (size_t)i * D_DIM);
      short4* dst = (short4*)(Ab + (size_t)i * D_DIM);
      float s = 0.f;
#pragma unroll
      for (int c = 0; c < 4; ++c) {
        const float4 v = src[lane + c * 64];
        s += v.x * v.x + v.y * v.y + v.z * v.z + v.w * v.w;
        short4 o;
        o.x = (short)f2bf(v.x); o.y = (short)f2bf(v.y);
        o.z = (short)f2bf(v.z); o.w = (short)f2bf(v.w);
        dst[lane + c * 64] = o;
      }
#pragma unroll
      for (int off = 32; off; off >>= 1) s += __shfl_down(s, off);
      if (lane == 0) { ls += (double)s; lq += (double)s * (double)s; }
    }
    if (lane == 0) { wr2[w] = ls; wq2[w] = lq; }
    __syncthreads();
    if (tid == 0) {
      rowp[2 * blockIdx.x]     = wr2[0] + wr2[1] + wr2[2] + wr2[3];
      rowp[2 * blockIdx.x + 1] = wq2[0] + wq2[1] + wq2[2] + wq2[3];
    }
  } else {
    __shared__ int list[N_ROWS];
    __shared__ int lcnt;
    __shared__ float wred[4];
    const int c = blockIdx.x - 512;
    if (c >= N_CLS) return;
    if (tid == 0) lcnt = 0;
    __syncthreads();
    for (int j = tid; j < N_ROWS; j += 256)
      if (target[j] == c) { int p = atomicAdd(&lcnt, 1); list[p] = j; }
    __syncthreads();
    const int n = lcnt;
    float4 acc = make_float4(0.f, 0.f, 0.f, 0.f);
    for (int m = 0; m < n; ++m) {
      const float4 v = *(const float4*)(A + (size_t)list[m] * D_DIM + tid * 4);
      acc.x += v.x; acc.y += v.y; acc.z += v.z; acc.w += v.w;
    }
    float s = acc.x * acc.x + acc.y * acc.y + acc.z * acc.z + acc.w * acc.w;
#pragma unroll
    for (int off = 32; off; off >>= 1) s += __shfl_down(s, off);
    if (lane == 0) wred[w] = s;
    __syncthreads();
    if (tid == 0) {
      cssp[c] = (double)(wred[0] + wred[1] + wred[2] + wred[3]);
      cntp[c] = n;
    }
  }
}

// ---------------------------------------------------------------------------
// kgram: block b = (kc = b&7, tile = b>>3 -> t1 = tile>>3, t2 = tile&7).
// Computes partial M-tile[t1][t2] over rows [kc*512, kc*512+512) and stores
// raw fp32 accumulators to slab.  256 thr, 4 waves 2x2 (64x64/wave, 4x4 acc).
// LDS: As/Bs [2 bufs][128 d][64 k] bf16, XOR-swizzled (chunk ^= d&7).
// Staging: reg micro-transpose (8k x 4d per thread): 8 short4 global loads ->
// 4 short8 ds_write_b128 per panel.  Loads issued 2 K-steps ahead.
// ---------------------------------------------------------------------------
__global__ void __launch_bounds__(256, 2) kgram(const short* __restrict__ Ab,
                                                float* __restrict__ slab) {
  __shared__ __align__(16) short As[2][128 * 64];   // 2 x 16 KB
  __shared__ __align__(16) short Bs[2][128 * 64];   // 2 x 16 KB
  const int tid = threadIdx.x, lane = tid & 63, w = tid >> 6;

  const int kc = blockIdx.x & 7;           // chunk-per-XCD
  const int tile = blockIdx.x >> 3;        // 0..63
  const int t1 = tile >> 3, t2 = tile & 7;
  const size_t rowbase = (size_t)kc * CHUNK;
  const int da = t1 * 128, db = t2 * 128;

  f32x4 acc[4][4];
#pragma unroll
  for (int m = 0; m < 4; ++m)
#pragma unroll
    for (int n = 0; n < 4; ++n) acc[m][n] = (f32x4){0.f, 0.f, 0.f, 0.f};

  const int wm = w >> 1, wn = w & 1;       // wave tile 64x64
  const int row16 = lane & 15, ck = lane >> 4;

  // staging map: thread -> d-group d4 (x4 cols), k-group k8 (x8 rows)
  const int d4 = tid & 31;
  const int k8 = tid >> 5;                 // 0..7

  short4 inA[8], inB[8];

#define LOADT(t)                                                            \
  do {                                                                      \
    const size_t r0 = rowbase + (size_t)(t) * 64 + k8 * 8;                  \
    _Pragma("unroll")                                                       \
    for (int kk = 0; kk < 8; ++kk) {                                        \
      inA[kk] = *(const short4*)(Ab + (r0 + kk) * D_DIM + da + d4 * 4);     \
      inB[kk] = *(const short4*)(Ab + (r0 + kk) * D_DIM + db + d4 * 4);     \
    }                                                                       \
  } while (0)

#define WRT(buf)                                                            \
  do {                                                                      \
    _Pragma("unroll")                                                       \
    for (int j = 0; j < 4; ++j) {                                           \
      short8 oa, ob;                                                        \
      _Pragma("unroll")                                                     \
      for (int kk = 0; kk < 8; ++kk) {                                      \
        oa[kk] = ((const short*)&inA[kk])[j];                               \
        ob[kk] = ((const short*)&inB[kk])[j];                               \
      }                                                                     \
      const int dl = d4 * 4 + j;                                            \
      const int cp = k8 ^ (dl & 7);                                         \
      *(short8*)((char*)As[buf] + dl * 128 + cp * 16) = oa;                 \
      *(short8*)((char*)Bs[buf] + dl * 128 + cp * 16) = ob;                 \
    }                                                                       \
  } while (0)

#define COMPUTE(buf)                                                        \
  do {                                                                      \
    _Pragma("unroll")                                                       \
    for (int ks = 0; ks < 2; ++ks) {                                        \
      short8 a[4], bb[4];                                                   \
      const int cpo = ((ks * 4 + ck) ^ (row16 & 7)) * 16;                   \
      _Pragma("unroll")                                                     \
      for (int m = 0; m < 4; ++m) {                                         \
        const int dl = wm * 64 + m * 16 + row16;                            \
        a[m] = *(const short8*)((const char*)As[buf] + dl * 128 + cpo);     \
      }                                                                     \
      _Pragma("unroll")                                                     \
      for (int n = 0; n < 4; ++n) {                                         \
        const int dl = wn * 64 + n * 16 + row16;                            \
        bb[n] = *(const short8*)((const char*)Bs[buf] + dl * 128 + cpo);    \
      }                                                                     \
      _Pragma("unroll")                                                     \
      for (int m = 0; m < 4; ++m)                                           \
        _Pragma("unroll")                                                   \
        for (int n = 0; n < 4; ++n)                                         \
          acc[m][n] = __builtin_amdgcn_mfma_f32_16x16x32_bf16(a[m], bb[n],  \
                                                              acc[m][n], 0, 0, 0); \
    }                                                                       \
  } while (0)

  LOADT(0);
  WRT(0);
  LOADT(1);
  __syncthreads();
#pragma unroll 1
  for (int t = 0; t < KSTEPS; ++t) {
    COMPUTE(t & 1);
    if (t < KSTEPS - 1) {
      WRT((t + 1) & 1);                 // regs from LOADT(t+1)
      if (t < KSTEPS - 2) LOADT(t + 2); // issue 2 steps ahead
    }
    __syncthreads();
  }
#undef LOADT
#undef WRT
#undef COMPUTE

  // store raw accumulators: slab[b][frag 0..15][tid] as f32x4
  f32x4* sp = (f32x4*)slab + (size_t)blockIdx.x * 16 * 256 + tid;
#pragma unroll
  for (int m = 0; m < 4; ++m)
#pragma unroll
    for (int n = 0; n < 4; ++n)
      sp[(size_t)(m * 4 + n) * 256] = acc[m][n];
}

// ---------------------------------------------------------------------------
// kred: per d-tile, sum the 8 chunk slabs elementwise, square, reduce.
// Full matrix -> no masks.  Grid 64 x 256 thr.
// ---------------------------------------------------------------------------
__global__ void __launch_bounds__(256) kred(const float* __restrict__ slab,
                                            double* __restrict__ frobp) {
  __shared__ double wred[4];
  const int tid = threadIdx.x, lane = tid & 63, w = tid >> 6;
  const int tile = blockIdx.x;
  const f32x4* sb = (const f32x4*)slab;

  float fs = 0.f;
#pragma unroll
  for (int f = 0; f < 16; ++f) {
    f32x4 v = (f32x4){0.f, 0.f, 0.f, 0.f};
#pragma unroll
    for (int kc = 0; kc < KC; ++kc)
      v += sb[((size_t)(kc + 8 * tile) * 16 + f) * 256 + tid];
    fs += v[0] * v[0] + v[1] * v[1] + v[2] * v[2] + v[3] * v[3];
  }
#pragma unroll
  for (int off = 32; off; off >>= 1) fs += __shfl_down(fs, off);
  if (lane == 0) wred[w] = (double)fs;
  __syncthreads();
  if (tid == 0)
    frobp[tile] = wred[0] + wred[1] + wred[2] + wred[3];
}

// ---------------------------------------------------------------------------
// kfinal: fp64 reduce + scalar math.
// ---------------------------------------------------------------------------
__global__ void __launch_bounds__(256) kfinal(const double* __restrict__ rowp,
                                              const double* __restrict__ cssp,
                                              const int* __restrict__ cntp,
                                              const double* __restrict__ frobp,
                                              float* __restrict__ out) {
  __shared__ double red[256];
  const int tid = threadIdx.x;
  double lsum = 0.0, lsq = 0.0, lcss = 0.0, lcnn = 0.0, lfr = 0.0;
  for (int i = tid; i < 512; i += 256) {
    lsum += rowp[2 * i];
    lsq  += rowp[2 * i + 1];
  }
  for (int c = tid; c < N_CLS; c += 256) {
    lcss += cssp[c];
    const double nc = (double)cntp[c];
    lcnn += nc * nc;
  }
  if (tid < 64) lfr = frobp[tid];

  double vals[5] = {lsum, lsq, lcss, lcnn, lfr};
  double res[5];
  for (int v = 0; v < 5; ++v) {
    red[tid] = vals[v];
    __syncthreads();
    for (int s = 128; s; s >>= 1) {
      if (tid < s) red[tid] += red[tid + s];
      __syncthreads();
    }
    res[v] = red[0];
    __syncthreads();
  }
  if (tid == 0) {
    const double sumr = res[0], sumq = res[1], css = res[2], cnn = res[3], F = res[4];
    const double S1 = 0.5 * (css - sumr);
    const double S2 = 0.5 * (cnn - (double)N_ROWS);
    const double S3 = 0.5 * (F - sumq);
    out[0] = (float)(-(S1 / (S2 * sqrt(S3))));
  }
}

extern "C" void kernel_launch(void* const* d_in, const int* in_sizes, int n_in,
                              void* d_out, int out_size, void* d_ws, size_t ws_size,
                              hipStream_t stream) {
  const float* A = (const float*)d_in[0];
  const int* target = (const int*)d_in[1];
  float* out = (float*)d_out;

  char* ws = (char*)d_ws;
  short*  Ab    = (short*)ws;                      // [0, 8388608)
  double* rowp  = (double*)(ws + 8388608);         // 1024 doubles -> 8396800
  double* cssp  = (double*)(ws + 8396800);         // 1000 doubles -> 8404800
  int*    cntp  = (int*)   (ws + 8404800);         // 1000 ints    -> 8408800
  double* frobp = (double*)(ws + 8408800);         // 64 doubles   -> 8409312
  float*  slab  = (float*) (ws + 8409312);         // 33,554,432 B -> 41,963,744

  kprep<<<512 + N_CLS, 256, 0, stream>>>(A, target, Ab, rowp, cssp, cntp);
  kgram<<<512, 256, 0, stream>>>(Ab, slab);
  kred<<<64, 256, 0, stream>>>(slab, frobp);
  kfinal<<<1, 256, 0, stream>>>(rowp, cssp, cntp, frobp, out);
}